// Round 4
// 624.933 us; speedup vs baseline: 1.0634x; 1.0634x over previous
//
#include <hip/hip_runtime.h>
#include <math.h>

// Problem constants (fixed by setup_inputs)
#define CCH 16
#define HH 256
#define WW 512
#define ND 32
#define HWSZ (HH * WW)
#define BASELINE 0.24f

// Native clang vector type — required by __builtin_nontemporal_{load,store}
// (HIP's float4 is a HIP_vector_type class and is rejected by the builtin).
typedef float f4 __attribute__((ext_vector_type(4)));

// Pass 1: transpose y [C,H,W] -> yt [H,W,C] (channel-innermost, 64B per pixel)
__global__ __launch_bounds__(256) void transpose_y_kernel(
    const float* __restrict__ y, float* __restrict__ yt)
{
    int p = blockIdx.x * blockDim.x + threadIdx.x;  // pixel index over H*W
    if (p >= HWSZ) return;
    float v[CCH];
    #pragma unroll
    for (int c = 0; c < CCH; ++c) v[c] = y[c * HWSZ + p];
    f4* dst = (f4*)(yt + (size_t)p * CCH);
    #pragma unroll
    for (int j = 0; j < 4; ++j) {
        f4 t = { v[4 * j], v[4 * j + 1], v[4 * j + 2], v[4 * j + 3] };
        dst[j] = t;
    }
}

// Pass 2a: reference half = broadcast x over disparity.
// One thread per (c, 4-pixel group): 1 f4 load, 32 f4 NT stores.
__global__ __launch_bounds__(256) void broadcast_x_kernel(
    const f4* __restrict__ x4, f4* __restrict__ out4)
{
    int p4 = blockIdx.x * 256 + threadIdx.x;   // 0 .. HWSZ/4-1  (gridDim.x = 128)
    int c  = blockIdx.y;                       // 0 .. 15
    f4 v = __builtin_nontemporal_load(&x4[(size_t)c * (HWSZ / 4) + p4]);
    f4* base = out4 + (size_t)c * (size_t)ND * (HWSZ / 4) + p4;
    #pragma unroll
    for (int d = 0; d < ND; ++d)
        __builtin_nontemporal_store(v, base + (size_t)d * (HWSZ / 4));
}

// Pass 2b: warped half only. Block: 256 threads = 4 disparities x 64 w-pixels.
// Grid: (ND/4, W/64, H) -- d fastest-dispatched so all 32 disparities of an
// (h, w-tile), which share the same ~36 y-rows, are co-resident and the
// gather working set stays cache-hot. Output stores are non-temporal so the
// 256 MiB write stream does not evict the yt gather lines from L2.
__global__ __launch_bounds__(256) void warp_kernel(
    const float4* __restrict__ yt4,   // [H*W][4] float4 (channel-innermost)
    const float* __restrict__ depth,
    float* __restrict__ out)
{
    int d = blockIdx.x * 4 + (threadIdx.x >> 6);
    int w = blockIdx.y * 64 + (threadIdx.x & 63);
    int h = blockIdx.z;
    int p = h * WW + w;

    float dep = __builtin_nontemporal_load(&depth[d * HWSZ + p]);

    // theta for this row (equirectangular, pixel-centered)
    float theta = ((float)h + 0.5f) * (float)(M_PI / HH) - (float)(M_PI / 2.0);
    float st, ct;
    sincosf(theta, &st, &ct);

    // vertical angular shift -> pixel rows
    float dth = atanf((dep * st + BASELINE) / (dep * ct)) - theta;
    float d_v = dth * (float)(HH / M_PI);
    float y_px = isfinite(d_v) ? ((float)h + d_v) : 0.0f;

    // faithful grid_sample(align_corners=False) unnormalization,
    // same arithmetic order as the reference
    float cx = (float)w / ((WW - 1.0f) * 0.5f) - 1.0f;
    float cy = y_px   / ((HH - 1.0f) * 0.5f) - 1.0f;
    float ix = ((cx + 1.0f) * (float)WW - 1.0f) * 0.5f;
    float iy = ((cy + 1.0f) * (float)HH - 1.0f) * 0.5f;

    float x0f = floorf(ix);
    float y0f = floorf(iy);
    float wx1 = ix - x0f;
    float wy1 = iy - y0f;
    float wx0 = 1.0f - wx1;
    float wy0 = 1.0f - wy1;

    int x0 = (int)x0f;
    int y0 = (int)y0f;
    int x1 = x0 + 1;
    int y1 = y0 + 1;

    float vx0 = (x0 >= 0 && x0 <= WW - 1) ? 1.0f : 0.0f;
    float vx1 = (x1 >= 0 && x1 <= WW - 1) ? 1.0f : 0.0f;
    float vy0 = (y0 >= 0 && y0 <= HH - 1) ? 1.0f : 0.0f;
    float vy1 = (y1 >= 0 && y1 <= HH - 1) ? 1.0f : 0.0f;

    int x0c = min(max(x0, 0), WW - 1);
    int x1c = min(max(x1, 0), WW - 1);
    int y0c = min(max(y0, 0), HH - 1);
    int y1c = min(max(y1, 0), HH - 1);

    float w00 = wx0 * wy0 * vx0 * vy0;
    float w10 = wx1 * wy0 * vx1 * vy0;
    float w01 = wx0 * wy1 * vx0 * vy1;
    float w11 = wx1 * wy1 * vx1 * vy1;

    // corner bases in float4 units (each corner = 16 floats = 4 float4 = 64B)
    int b00 = (y0c * WW + x0c) * 4;
    int b10 = (y0c * WW + x1c) * 4;
    int b01 = (y1c * WW + x0c) * 4;
    int b11 = (y1c * WW + x1c) * 4;

    float4 acc[4];
    #pragma unroll
    for (int j = 0; j < 4; ++j) {
        float4 a = yt4[b00 + j];
        acc[j] = make_float4(a.x * w00, a.y * w00, a.z * w00, a.w * w00);
    }
    #pragma unroll
    for (int j = 0; j < 4; ++j) {
        float4 a = yt4[b10 + j];
        acc[j].x += a.x * w10; acc[j].y += a.y * w10;
        acc[j].z += a.z * w10; acc[j].w += a.w * w10;
    }
    #pragma unroll
    for (int j = 0; j < 4; ++j) {
        float4 a = yt4[b01 + j];
        acc[j].x += a.x * w01; acc[j].y += a.y * w01;
        acc[j].z += a.z * w01; acc[j].w += a.w * w01;
    }
    #pragma unroll
    for (int j = 0; j < 4; ++j) {
        float4 a = yt4[b11 + j];
        acc[j].x += a.x * w11; acc[j].y += a.y * w11;
        acc[j].z += a.z * w11; acc[j].w += a.w * w11;
    }

    const float* accf = (const float*)acc;
    size_t dp = (size_t)d * HWSZ + p;

    #pragma unroll
    for (int c = 0; c < CCH; ++c) {
        __builtin_nontemporal_store(
            accf[c], &out[(size_t)(CCH + c) * ((size_t)ND * HWSZ) + dp]);
    }
}

extern "C" void kernel_launch(void* const* d_in, const int* in_sizes, int n_in,
                              void* d_out, int out_size, void* d_ws, size_t ws_size,
                              hipStream_t stream) {
    const float* x = (const float*)d_in[0];
    const float* y = (const float*)d_in[1];
    const float* depth = (const float*)d_in[2];
    float* out = (float*)d_out;
    float* yt = (float*)d_ws;   // needs H*W*16*4 = 8 MB

    transpose_y_kernel<<<(HWSZ + 255) / 256, 256, 0, stream>>>(y, yt);

    dim3 bgrid(HWSZ / 4 / 256, CCH, 1);   // (128, 16)
    broadcast_x_kernel<<<bgrid, 256, 0, stream>>>(
        (const f4*)x, (f4*)out);

    dim3 wgrid(ND / 4, WW / 64, HH);      // (8, 8, 256)
    warp_kernel<<<wgrid, 256, 0, stream>>>(
        (const float4*)yt, depth, out);
}